// Round 8
// baseline (182.503 us; speedup 1.0000x reference)
//
#include <hip/hip_runtime.h>
#include <math.h>

#define EPSV 1e-4f
#define SCHUNK 64

// Relaxed agent-scope atomics: point-wise LLC-coherent accesses (sc1), NO
// cache-wide invalidate/writeback (acquire/release emit buffer_inv/buffer_wbl2
// on gfx950 -> measured 693us disaster in round 1). Ordering done manually
// with s_waitcnt vmcnt(0) before flag stores. NOTE: within a single kernel,
// NORMAL stores are NOT cross-XCD visible (per-XCD L2, write-back) -> every
// cross-block datum (bsum, sidx, aggE, aggP, flags) uses these helpers.
__device__ __forceinline__ float agent_load_f(const float* p) {
    return __hip_atomic_load(p, __ATOMIC_RELAXED, __HIP_MEMORY_SCOPE_AGENT);
}
__device__ __forceinline__ void agent_store_f(float* p, float v) {
    __hip_atomic_store(p, v, __ATOMIC_RELAXED, __HIP_MEMORY_SCOPE_AGENT);
}
__device__ __forceinline__ int agent_load_i(const int* p) {
    return __hip_atomic_load(p, __ATOMIC_RELAXED, __HIP_MEMORY_SCOPE_AGENT);
}
__device__ __forceinline__ void agent_store_i(int* p, int v) {
    __hip_atomic_store(p, v, __ATOMIC_RELAXED, __HIP_MEMORY_SCOPE_AGENT);
}

// ---------------- clear: scan flags + ticket + done + bflags ----------------
__global__ void clear_kernel(int* __restrict__ flags, int n) {
    int i = blockIdx.x * blockDim.x + threadIdx.x;
    if (i < n) flags[i] = 0;
}

// ---------------- fully fused kernel ----------------
// Grid = NC (2048) blocks x 512 threads. Ticket-ordered (resident-predecessor
// guarantee). Three phases:
//   A (tickets < nsb=256): fused b_flat scan -> sidx. Block sum of 1024
//     b-elements, publish, PARALLEL lookback (thread i spins on pred i,
//     O(1) depth), emit sidx via agent stores, bump 'done'. Runs BEFORE the
//     scan phase so it overlaps other blocks' pass-1; sidx isn't consumed
//     until after lookback (~40us in), phase A finishes in ~10us -> no stall.
//   B: r7-proven scan: SCHUNK=64, one channel/thread, z[64] entirely in VGPRs
//     (h read exactly ONCE, nontemporal), publish aggregate, decoupled
//     lookback (depth ~2: P/chunk ~ e^-64 -> prodAcc==0 fast).
//   C: wait done==nsb, load sh_j, finalize y_t = A_t*carry + z_t, scatter.
// Deadlock-free: every wait targets a strictly-lower ticket (resident) or
// phase-A blocks which never wait on scan state.
__global__ __launch_bounds__(512, 4) void fused_scan_kernel(
        const float* __restrict__ h,
        const int*   __restrict__ bflat,
        const float* __restrict__ psel,
        const int*   __restrict__ seq,
        float* __restrict__ out,
        float* __restrict__ aggE,   // [NC][d]
        float* __restrict__ aggP,   // [NC]
        int*   __restrict__ flags,  // [NC] scan flags | [NC]=ticket | [NC+1]=done | [NC+2..+nsb)=bflags
        int*   __restrict__ bsum,   // [nsb]
        int*   __restrict__ sidx,   // [L+1]
        int L, int d, int Louter, int NC, int nsb) {
    __shared__ float sh_a[SCHUNK];
    __shared__ float sh_p[SCHUNK];
    __shared__ float sh_A[SCHUNK];   // A_t = prod_{u<=t} a_u
    __shared__ int   sh_j[SCHUNK + 1];
    __shared__ int   sh_g;
    __shared__ float sh_Pbr;
    __shared__ int   red[512];
    __shared__ int   red2[512];

    int* ticket = flags + NC;
    int* done   = flags + NC + 1;
    int* bflags = flags + NC + 2;

    const int tid = threadIdx.x;
    if (tid == 0) sh_g = atomicAdd(ticket, 1);   // device-scope ticket
    __syncthreads();
    const int g  = sh_g;
    const int t0 = g * SCHUNK;
    const int nt = min(SCHUNK, L - t0);

    // ================= phase A: fused b_flat scan -> sidx =================
    for (int s = g; s < nsb; s += NC) {          // one iteration when NC>=nsb
        int base = s * 1024 + tid * 2;
        int v0 = (base     < Louter) ? bflat[base]     : 0;
        int v1 = (base + 1 < Louter) ? bflat[base + 1] : 0;
        int ssum = v0 + v1;
        red[tid] = ssum;
        __syncthreads();
        for (int off = 1; off < 512; off <<= 1) {   // inclusive Hillis-Steele
            int tv = red[tid];
            if (tid >= off) tv += red[tid - off];
            __syncthreads();
            red[tid] = tv;
            __syncthreads();
        }
        if (tid == 511) {                        // publish segment sum
            agent_store_i(&bsum[s], red[511]);
            asm volatile("s_waitcnt vmcnt(0)" ::: "memory");
            agent_store_i(&bflags[s], 1);
        }
        int pre = 0;                             // parallel lookback, O(1) depth
        if (tid < s) {
            while (agent_load_i(&bflags[tid]) == 0) __builtin_amdgcn_s_sleep(1);
            pre = agent_load_i(&bsum[tid]);
        }
        red2[tid] = pre;
        __syncthreads();
        for (int off = 256; off > 0; off >>= 1) {
            if (tid < off) red2[tid] += red2[tid + off];
            __syncthreads();
        }
        int cum = red[tid] - ssum + red2[0];     // exclusive global prefix at base
        cum += v0;
        if (v0 > 0 && cum - 1 >= 0 && cum - 1 < L)
            agent_store_i(&sidx[cum - 1], base);
        cum += v1;
        if (v1 > 0 && cum - 1 >= 0 && cum - 1 < L)
            agent_store_i(&sidx[cum - 1], base + 1);
        if (s == 0 && tid == 0)
            agent_store_i(&sidx[L], Louter);     // sentinel
    }
    if (g < nsb) {
        __syncthreads();                         // drain all waves' sidx stores
        if (tid == 0) atomicAdd(done, 1);        // device-scope RMW at LLC
    }

    // ================= phase B: scan (r7-proven) =================
    // prologue: per-timestep scalars (fused prep)
    if (tid < nt) {
        int t = t0 + tid;
        float p = psel[t];
        p = fminf(fmaxf(p, EPSV), 1.0f - EPSV);
        bool start = (t == 0) || (seq[t] != seq[t - 1]);
        sh_a[tid] = start ? 0.0f : (1.0f - p);   // exp(-dt) == 1-p exactly
        sh_p[tid] = p;                           // b_t = p*h
    }
    __syncthreads();

    // wave-0 log-step inclusive prefix-product -> sh_A (6 shfl_up steps)
    if (tid < 64) {
        float v = (tid < nt) ? sh_a[tid] : 1.0f;
#pragma unroll
        for (int off = 1; off < 64; off <<= 1) {
            float w = __shfl_up(v, off);
            if (tid >= off) v *= w;
        }
        sh_A[tid] = v;
    }
    __syncthreads();

    const int c = tid;
    const float* __restrict__ hp = h + (size_t)t0 * d + c;
    const bool full = (nt == SCHUNK);

    // ---- pass 1: local scan fully in registers, h read ONCE (nontemporal) ----
    float z[SCHUNK];
    float st = 0.0f;
    if (full) {
#pragma unroll
        for (int grp = 0; grp < SCHUNK / 8; ++grp) {
            float hb[8];
#pragma unroll
            for (int k = 0; k < 8; ++k)
                hb[k] = __builtin_nontemporal_load(hp + (size_t)(grp * 8 + k) * d);
#pragma unroll
            for (int k = 0; k < 8; ++k) {
                int t = grp * 8 + k;
                st = fmaf(sh_a[t], st, sh_p[t] * hb[k]);
                z[t] = st;                       // static index -> stays in VGPR
            }
        }
    } else {
        for (int t = 0; t < nt; ++t)
            st = fmaf(sh_a[t], st, sh_p[t] * hp[(size_t)t * d]);
    }

    // ---- publish aggregate (relaxed + waitcnt ordering) ----
    agent_store_f(&aggE[(size_t)g * d + c], st);
    __syncthreads();            // drains vmcnt -> all aggE stores at LLC
    if (tid == 0) {
        agent_store_f(&aggP[g], sh_A[nt - 1]);
        asm volatile("s_waitcnt vmcnt(0)" ::: "memory");  // aggP before flag
        agent_store_i(&flags[g], 1);
    }

    // ---- decoupled lookback: carry = state at end of chunk g-1 ----
    float carry = 0.0f;
    float prodAcc = 1.0f;
    for (int i = g - 1; i >= 0; --i) {
        if (tid == 0) {
            while (agent_load_i(&flags[i]) == 0) __builtin_amdgcn_s_sleep(1);
            sh_Pbr = agent_load_f(&aggP[i]);
        }
        __syncthreads();
        float Pi = sh_Pbr;
        carry = fmaf(prodAcc, agent_load_f(&aggE[(size_t)i * d + c]), carry);
        prodAcc *= Pi;                    // uniform across threads
        __syncthreads();                  // sh_Pbr reused next iteration
        if (prodAcc == 0.0f) break;       // e^-64/chunk -> 0 after ~2 steps
    }

    // ================= phase C: wait sidx ready, finalize + scatter =========
    if (tid == 0) {
        while (agent_load_i(done) < nsb) __builtin_amdgcn_s_sleep(8);
    }
    __syncthreads();
    if (tid <= nt) sh_j[tid] = agent_load_i(&sidx[t0 + tid]);  // LLC-hot
    __syncthreads();

    if (full) {
#pragma unroll
        for (int t = 0; t < SCHUNK; ++t) {
            float y = fmaf(sh_A[t], carry, z[t]);
            int j0 = max(sh_j[t], 0);
            int j1 = min(sh_j[t + 1], Louter);
            for (int j = j0; j < j1; ++j)
                __builtin_nontemporal_store(y, out + (size_t)j * d + c);
        }
    } else {
        // tail chunk (not hit when L%64==0): rescan with carry folded in
        float s2 = carry;
        for (int t = 0; t < nt; ++t) {
            s2 = fmaf(sh_a[t], s2, sh_p[t] * hp[(size_t)t * d]);
            int j0 = max(sh_j[t], 0);
            int j1 = min(sh_j[t + 1], Louter);
            for (int j = j0; j < j1; ++j)
                out[(size_t)j * d + c] = s2;
        }
    }
}

extern "C" void kernel_launch(void* const* d_in, const int* in_sizes, int n_in,
                              void* d_out, int out_size, void* d_ws, size_t ws_size,
                              hipStream_t stream) {
    const float* h     = (const float*)d_in[0];
    const int*   bflat = (const int*)d_in[1];
    const float* psel  = (const float*)d_in[2];
    const int*   seq   = (const int*)d_in[3];
    float* out = (float*)d_out;

    const int L      = in_sizes[2];          // 131072
    const int Louter = in_sizes[1];          // 262144
    const int d      = in_sizes[0] / L;      // 512

    const int NC  = (L + SCHUNK - 1) / SCHUNK;   // 2048
    const int nsb = (Louter + 1023) / 1024;      // 256 b-scan segments

    // workspace layout (256B-aligned slices) — total ~4.6 MB
    char* ws = (char*)d_ws;
    size_t off = 0;
    auto alloc = [&](size_t bytes) -> void* {
        void* p = ws + off;
        off = (off + bytes + 255) & ~(size_t)255;
        return p;
    };
    float* aggE  = (float*)alloc((size_t)NC * d * 4);
    float* aggP  = (float*)alloc((size_t)NC * 4);
    int*   flags = (int*)alloc((size_t)(NC + 2 + nsb) * 4); // +ticket +done +bflags
    int*   bsum  = (int*)alloc((size_t)nsb * 4);
    int*   sidx  = (int*)alloc((size_t)(L + 1) * 4);
    (void)ws_size;

    const int nclr = NC + 2 + nsb;
    clear_kernel<<<(nclr + 255) / 256, 256, 0, stream>>>(flags, nclr);

    fused_scan_kernel<<<NC, d, 0, stream>>>(h, bflat, psel, seq, out,
                                            aggE, aggP, flags, bsum, sidx,
                                            L, d, Louter, NC, nsb);
}